// Round 12
// baseline (5177.826 us; speedup 1.0000x reference)
//
#include <hip/hip_runtime.h>
#include <math.h>

// Problem constants
#define Bb 64
#define Tt 512
#define Ee 128
#define Hq 256
#define G3 768      // 3*H
#define KK 16

#define THRG 512    // gru threads per block

// Workspace layout (in floats).  Budget: 256 MiB.
#define OFF_WTF  0
#define OFF_WTB  196608                        // 768*256
#define OFF_XPF  393216
#define OFF_XPB  (OFF_XPF + 25165824)          // 32768*768
#define OFF_EM   (OFF_XPB + 25165824)
#define OFF_SLOT (OFF_EM + 524288)             // 2*128*256 floats
#define OFF_FLAG (OFF_SLOT + 65536)            // 256 ints
#define WS_FLOATS ((size_t)(OFF_FLAG + 256))

// Inline-asm 16B load: the destination is an asm def, so the register
// allocator can NEVER rematerialize it as a per-iteration reload (the
// mechanism that defeated VGPR residency in rounds 7/8/11).
__device__ inline float4 ld_pin(const float4* p)
{
    float4 r;
    asm volatile("global_load_dwordx4 %0, %1, off\n\ts_waitcnt vmcnt(0)"
                 : "=v"(r) : "v"(p) : "memory");
    return r;
}

// ---------------------------------------------------------------------------
// Repack w_hh (768x256, row g3 = gate*256+j, col k) into quad-gate layout:
//   float4 at index (Q*3+gate)*256+j holds w[gate,j][4Q..4Q+3].
__global__ __launch_bounds__(256) void transpose_whh(const float* __restrict__ w,
                                                     float* __restrict__ wt)
{
    const int idx = blockIdx.x * 256 + threadIdx.x;
    if (idx < G3 * Hq) {
        const int g3 = idx >> 8;       // 0..767
        const int k  = idx & 255;      // 0..255
        const int gate = g3 >> 8;      // 0..2
        const int j    = g3 & 255;
        const int Q = k >> 2, e = k & 3;
        wt[(size_t)(((Q * 3 + gate) << 8) + j) * 4 + e] = w[idx];
    }
}

// ---------------------------------------------------------------------------
// Fused embedding-gather + input projection for both directions.
__global__ __launch_bounds__(256) void proj_kernel(
    const int* __restrict__ x, const float* __restrict__ embed,
    const float* __restrict__ wf, const float* __restrict__ wb,
    const float* __restrict__ bihf, const float* __restrict__ bhhf,
    const float* __restrict__ bihb, const float* __restrict__ bhhb,
    float* __restrict__ xpf, float* __restrict__ xpb)
{
    __shared__ float As[64][66];
    __shared__ float Bs[64][66];
    const int bi = blockIdx.x;
    const int mb = bi / 24, nb = bi % 24;
    const int m0 = mb * 64, n0 = nb * 64;
    const int tid = threadIdx.x;
    const int tx = tid & 15, ty = tid >> 4;
    float acc[4][4] = {};

    for (int kc = 0; kc < 128; kc += 64) {
        __syncthreads();
        for (int it = 0; it < 4; ++it) {
            const int l  = it * 256 + tid;
            const int mi = l >> 4;
            const int k4 = (l & 15) << 2;
            const int row = x[m0 + mi];
            const float4 v = *(const float4*)(embed + (size_t)row * Ee + kc + k4);
            As[k4 + 0][mi] = v.x; As[k4 + 1][mi] = v.y;
            As[k4 + 2][mi] = v.z; As[k4 + 3][mi] = v.w;
        }
        for (int it = 0; it < 4; ++it) {
            const int l  = it * 256 + tid;
            const int ni = l >> 4;
            const int k4 = (l & 15) << 2;
            const int g  = n0 + ni;
            const float* wsrc = (g < G3) ? (wf + (size_t)g * Ee)
                                         : (wb + (size_t)(g - G3) * Ee);
            const float4 v = *(const float4*)(wsrc + kc + k4);
            Bs[k4 + 0][ni] = v.x; Bs[k4 + 1][ni] = v.y;
            Bs[k4 + 2][ni] = v.z; Bs[k4 + 3][ni] = v.w;
        }
        __syncthreads();
        for (int k = 0; k < 64; ++k) {
            const float a0 = As[k][ty];      const float a1 = As[k][ty + 16];
            const float a2 = As[k][ty + 32]; const float a3 = As[k][ty + 48];
            const float b0 = Bs[k][tx];      const float b1 = Bs[k][tx + 16];
            const float b2 = Bs[k][tx + 32]; const float b3 = Bs[k][tx + 48];
            acc[0][0] += a0 * b0; acc[0][1] += a0 * b1; acc[0][2] += a0 * b2; acc[0][3] += a0 * b3;
            acc[1][0] += a1 * b0; acc[1][1] += a1 * b1; acc[1][2] += a1 * b2; acc[1][3] += a1 * b3;
            acc[2][0] += a2 * b0; acc[2][1] += a2 * b1; acc[2][2] += a2 * b2; acc[2][3] += a2 * b3;
            acc[3][0] += a3 * b0; acc[3][1] += a3 * b1; acc[3][2] += a3 * b2; acc[3][3] += a3 * b3;
        }
    }
#pragma unroll
    for (int i = 0; i < 4; ++i) {
        const int m = m0 + ty + 16 * i;
#pragma unroll
        for (int c = 0; c < 4; ++c) {
            const int g = n0 + tx + 16 * c;
            const float v = acc[i][c];
            if (g < G3) {
                const float bias = bihf[g] + (g < 2 * Hq ? bhhf[g] : 0.0f);
                xpf[(size_t)m * G3 + g] = v + bias;
            } else {
                const int g2 = g - G3;
                const float bias = bihb[g2] + (g2 < 2 * Hq ? bhhb[g2] : 0.0f);
                xpb[(size_t)m * G3 + g2] = v + bias;
            }
        }
    }
}

// ---------------------------------------------------------------------------
// GRU recurrence, J=2 pair-split with VGPR-resident weights.
// 256 blocks = (half P = bid>>7) x (chain c = bid&127). 512 threads:
// thread (j = tid&127, ks = tid>>7) owns hidden unit jg = P*128+j and
// k-quarter [ks*64, ks*64+64): 48 float4 weights PERMANENTLY in VGPRs
// (asm-pinned). Per step: stage partner h-half via MALL atomics, compute
// r/z/n partial dots from LDS h broadcasts, k-reduce via LDS, combine,
// publish own h-half (release flag).  Weight memory traffic/step = 0.
__global__ __launch_bounds__(THRG)
__attribute__((amdgpu_waves_per_eu(2, 2)))
void gru_kernel(const float* __restrict__ wtq0,
                float* __restrict__ xpf, float* __restrict__ xpb,
                const float* __restrict__ bhhf, const float* __restrict__ bhhb,
                float* __restrict__ slot, int* __restrict__ flags)
{
    __shared__ float sh_h[Hq];            // full h (both halves)
    __shared__ float sh_p[4][3][128];     // k-partials

    const int bid = blockIdx.x;
    const int P   = bid >> 7;             // hidden-half 0/1
    const int c   = bid & 127;            // chain
    const int dir = c >> 6;
    const int b   = c & 63;
    const int tid = threadIdx.x;
    const int j   = tid & 127;
    const int ks  = tid >> 7;             // k-quarter 0..3
    const int jg  = P * 128 + j;

    const float4* wtq4 = (const float4*)(wtq0 + (size_t)dir * (G3 * Hq));
    float* xp = (dir ? xpb : xpf) + (size_t)b * Tt * G3;

    // asm-pinned weights: gate {r,z,n}, quads Q = ks*16 + qq, column jg
    float4 wr[16], wz[16], wn[16];
#pragma unroll
    for (int qq = 0; qq < 16; ++qq) {
        const int Q = ks * 16 + qq;
        wr[qq] = ld_pin(wtq4 + (Q * 3 + 0) * Hq + jg);
        wz[qq] = ld_pin(wtq4 + (Q * 3 + 1) * Hq + jg);
        wn[qq] = ld_pin(wtq4 + (Q * 3 + 2) * Hq + jg);
    }

    const float bhn = (dir ? bhhb : bhhf)[2 * Hq + jg];
    const int pflag = c * 2 + (1 - P);    // partner's flag
    const int oflag = c * 2 + P;          // own flag
    float hprev = 0.0f;
    if (tid < 128) {
        sh_h[P * 128 + tid] = 0.0f;
        sh_h[(1 - P) * 128 + tid] = 0.0f;
    }
    __syncthreads();

    for (int ti = 0; ti < Tt; ++ti) {
        const int t = dir ? (Tt - 1 - ti) : ti;
        float* xrow = xp + (size_t)t * G3;

        // x parts (independent of h) -- issue before the poll
        float xr = 0.f, xz = 0.f, xn = 0.f;
        if (tid < 128) {
            xr = xrow[P * 128 + tid];
            xz = xrow[Hq + P * 128 + tid];
            xn = xrow[2 * Hq + P * 128 + tid];
        }

        float ar = 0.0f, az = 0.0f, an = 0.0f;

        if (ti > 0) {
            // stage partner h-half (tid<128): poll flag, MALL-read slot
            if (tid < 128) {
                while (__hip_atomic_load(&flags[pflag], __ATOMIC_ACQUIRE,
                                         __HIP_MEMORY_SCOPE_AGENT) < ti) {
                    __builtin_amdgcn_s_sleep(2);
                }
                const float hv = __hip_atomic_load(
                    &slot[((ti & 1) * 128 + c) * 256 + (1 - P) * 128 + tid],
                    __ATOMIC_RELAXED, __HIP_MEMORY_SCOPE_AGENT);
                sh_h[(1 - P) * 128 + tid] = hv;
            }
            __syncthreads();

            const float4* h4b = (const float4*)sh_h;   // 64 quads, global k
#pragma unroll
            for (int qq = 0; qq < 16; ++qq) {
                const float4 h4 = h4b[ks * 16 + qq];   // wave-uniform: broadcast
                ar += h4.x*wr[qq].x + h4.y*wr[qq].y + h4.z*wr[qq].z + h4.w*wr[qq].w;
                az += h4.x*wz[qq].x + h4.y*wz[qq].y + h4.z*wz[qq].z + h4.w*wz[qq].w;
                an += h4.x*wn[qq].x + h4.y*wn[qq].y + h4.z*wn[qq].z + h4.w*wn[qq].w;
            }
        }

        sh_p[ks][0][j] = ar;
        sh_p[ks][1][j] = az;
        sh_p[ks][2][j] = an;
        __syncthreads();

        if (tid < 128) {
            const float far_ = sh_p[0][0][tid] + sh_p[1][0][tid] + sh_p[2][0][tid] + sh_p[3][0][tid];
            const float faz_ = sh_p[0][1][tid] + sh_p[1][1][tid] + sh_p[2][1][tid] + sh_p[3][1][tid];
            const float fan_ = sh_p[0][2][tid] + sh_p[1][2][tid] + sh_p[2][2][tid] + sh_p[3][2][tid];
            const float r = 1.0f / (1.0f + expf(-(xr + far_)));
            const float z = 1.0f / (1.0f + expf(-(xz + faz_)));
            const float n = tanhf(xn + r * (fan_ + bhn));
            const float hnew = (1.0f - z) * n + z * hprev;
            hprev = hnew;
            sh_h[P * 128 + tid] = hnew;               // local half, next step
            xrow[P * 128 + tid] = hnew;               // in-place h store (em)
            __hip_atomic_store(
                &slot[(((ti + 1) & 1) * 128 + c) * 256 + P * 128 + tid], hnew,
                __ATOMIC_RELAXED, __HIP_MEMORY_SCOPE_AGENT);
        }
        __syncthreads();   // drains all waves' vmem -> slot stores visible
        if (tid == 0)
            __hip_atomic_store(&flags[oflag], ti + 1, __ATOMIC_RELEASE,
                               __HIP_MEMORY_SCOPE_AGENT);
    }
}

// ---------------------------------------------------------------------------
// em[m][n] = sum_k hf[m][k]*fcw[n][k] + sum_k hb[m][k]*fcw[n][256+k] + fcb[n]
__global__ __launch_bounds__(256) void em_kernel(
    const float* __restrict__ hf, const float* __restrict__ hb,
    const float* __restrict__ fcw, const float* __restrict__ fcb,
    float* __restrict__ em)
{
    __shared__ float ht[16][129];
    __shared__ float wt2[16][129];
    const int m0 = blockIdx.x * 16;
    const int tid = threadIdx.x;
    const int r = tid >> 4, n = tid & 15;
    float acc = 0.0f;
    for (int s = 0; s < 2; ++s) {
        const float* src = s ? hb : hf;
        for (int kc = 0; kc < Hq; kc += 128) {
            __syncthreads();
            for (int it = 0; it < 8; ++it) {
                const int l = it * 256 + tid;
                const int rr = l >> 7, k = l & 127;
                ht[rr][k] = src[(size_t)(m0 + rr) * G3 + kc + k];
            }
            for (int it = 0; it < 8; ++it) {
                const int l = it * 256 + tid;
                const int rr = l >> 7, k = l & 127;
                wt2[rr][k] = fcw[(size_t)rr * (2 * Hq) + s * Hq + kc + k];
            }
            __syncthreads();
            for (int k = 0; k < 128; ++k)
                acc += ht[r][k] * wt2[n][k];
        }
    }
    em[(size_t)(m0 + r) * KK + n] = acc + fcb[n];
}

// ---------------------------------------------------------------------------
// Viterbi: one wave per batch. Lanes 0..15 = states. Backpointers in LDS.
__global__ __launch_bounds__(64) void viterbi_kernel(
    const float* __restrict__ em, const int* __restrict__ y,
    const float* __restrict__ tr, float* __restrict__ out)
{
    __shared__ unsigned char bps[(Tt - 1) * KK];
    __shared__ unsigned char msk[Tt];
    const int b = blockIdx.x;
    const int lane = threadIdx.x;
    if (lane >= KK) return;
    const int j = lane;
    float tc[KK];
#pragma unroll
    for (int i = 0; i < KK; ++i) tc[i] = tr[i * KK + j];
    const float* erow = em + (size_t)b * Tt * KK;
    const int* yrow = y + b * Tt;
    float s = tr[1 * KK + j] + erow[j];            // BOS row + em[:,0]
    if (j == 0) msk[0] = (unsigned char)(yrow[0] != 0);
    float e1 = erow[1 * KK + j];  int y1v = yrow[1];
    float e2 = erow[2 * KK + j];  int y2v = yrow[2];
    for (int t = 1; t < Tt; ++t) {
        const float e = e1; const int yt = y1v;
        e1 = e2; y1v = y2v;
        if (t + 2 < Tt) { e2 = erow[(size_t)(t + 2) * KK + j]; y2v = yrow[t + 2]; }
        float best = -3.0e38f; int arg = 0;
#pragma unroll
        for (int i = 0; i < KK; ++i) {
            const float si = __shfl(s, i, KK);
            const float c = si + tc[i];
            if (c > best) { best = c; arg = i; }   // strict >, first-max = argmax
        }
        best += e;
        const bool m = (yt != 0);
        if (m) s = best;
        bps[(t - 1) * KK + j] = m ? (unsigned char)arg : (unsigned char)j;
        if (j == 0) msk[t] = (unsigned char)m;
    }
    s += tr[j * KK + 2];                           // + trans[:,EOS]
    float bs = -3.0e38f; int bt = 0;
#pragma unroll
    for (int i = 0; i < KK; ++i) {
        const float si = __shfl(s, i, KK);
        if (si > bs) { bs = si; bt = i; }
    }
    if (j == 0) {
        out[b] = bs;
        float* path = out + Bb + (size_t)b * Tt;
        int tag = bt;
        path[Tt - 1] = msk[Tt - 1] ? (float)tag : 0.0f;
        for (int t = Tt - 2; t >= 0; --t) {
            tag = bps[t * KK + tag];
            path[t] = msk[t] ? (float)tag : 0.0f;
        }
    }
}

// Diagnostic fallback if workspace is too small: park ws_size in out[0..63].
__global__ void ws_report_kernel(float* out, float v)
{
    if (threadIdx.x < 64) out[threadIdx.x] = v;
}

// ---------------------------------------------------------------------------
extern "C" void kernel_launch(void* const* d_in, const int* in_sizes, int n_in,
                              void* d_out, int out_size, void* d_ws, size_t ws_size,
                              hipStream_t stream)
{
    const int*   x     = (const int*)d_in[0];
    const int*   y     = (const int*)d_in[1];
    const float* emb   = (const float*)d_in[2];
    const float* wihf  = (const float*)d_in[3];
    const float* whhf  = (const float*)d_in[4];
    const float* bihf  = (const float*)d_in[5];
    const float* bhhf  = (const float*)d_in[6];
    const float* wihb  = (const float*)d_in[7];
    const float* whhb  = (const float*)d_in[8];
    const float* bihb  = (const float*)d_in[9];
    const float* bhhb  = (const float*)d_in[10];
    const float* fcw   = (const float*)d_in[11];
    const float* fcb   = (const float*)d_in[12];
    const float* trans = (const float*)d_in[13];
    float* out = (float*)d_out;
    float* ws  = (float*)d_ws;

    if (ws_size < WS_FLOATS * sizeof(float)) {
        ws_report_kernel<<<1, 64, 0, stream>>>(out, (float)ws_size);
        return;
    }

    // reset pair-sync flags (stale from previous replay / poisoned)
    hipMemsetAsync(ws + OFF_FLAG, 0, 256 * sizeof(int), stream);

    transpose_whh<<<768, 256, 0, stream>>>(whhf, ws + OFF_WTF);
    transpose_whh<<<768, 256, 0, stream>>>(whhb, ws + OFF_WTB);
    proj_kernel<<<12288, 256, 0, stream>>>(x, emb, wihf, wihb,
                                           bihf, bhhf, bihb, bhhb,
                                           ws + OFF_XPF, ws + OFF_XPB);
    gru_kernel<<<256, THRG, 0, stream>>>(ws + OFF_WTF,
                                         ws + OFF_XPF, ws + OFF_XPB,
                                         bhhf, bhhb,
                                         ws + OFF_SLOT,
                                         (int*)(ws + OFF_FLAG));
    em_kernel<<<2048, 256, 0, stream>>>(ws + OFF_XPF, ws + OFF_XPB, fcw, fcb,
                                        ws + OFF_EM);
    viterbi_kernel<<<64, 64, 0, stream>>>(ws + OFF_EM, y, trans, out);
}

// Round 13
// 4010.804 us; speedup vs baseline: 1.2910x; 1.2910x over previous
//
#include <hip/hip_runtime.h>
#include <math.h>

// Problem constants
#define Bb 64
#define Tt 512
#define Ee 128
#define Hq 256
#define G3 768      // 3*H
#define KK 16

// Workspace layout (in floats).  Budget: 256 MiB.
#define OFF_WTF  0
#define OFF_WTB  196608                        // 768*256
#define OFF_XPF  393216
#define OFF_XPB  (OFF_XPF + 25165824)          // 32768*768
#define OFF_EM   (OFF_XPB + 25165824)
#define OFF_SLOT (OFF_EM + 524288)             // 2 par x 2 dir x 64 b x 256 = 65536
#define OFF_FLAG (OFF_SLOT + 65536)            // 256 ints
#define WS_FLOATS ((size_t)(OFF_FLAG + 256))

// ---------------------------------------------------------------------------
// Repack w_hh (768x256, row g3 = gate*256+j, col k) into quad-gate layout:
//   float4 at index (Q*3+gate)*256+j holds w[gate,j][4Q..4Q+3].
__global__ __launch_bounds__(256) void transpose_whh(const float* __restrict__ w,
                                                     float* __restrict__ wt)
{
    const int idx = blockIdx.x * 256 + threadIdx.x;
    if (idx < G3 * Hq) {
        const int g3 = idx >> 8;       // 0..767
        const int k  = idx & 255;      // 0..255
        const int gate = g3 >> 8;      // 0..2
        const int j    = g3 & 255;
        const int Q = k >> 2, e = k & 3;
        wt[(size_t)(((Q * 3 + gate) << 8) + j) * 4 + e] = w[idx];
    }
}

// ---------------------------------------------------------------------------
// Fused embedding-gather + input projection for both directions.
__global__ __launch_bounds__(256) void proj_kernel(
    const int* __restrict__ x, const float* __restrict__ embed,
    const float* __restrict__ wf, const float* __restrict__ wb,
    const float* __restrict__ bihf, const float* __restrict__ bhhf,
    const float* __restrict__ bihb, const float* __restrict__ bhhb,
    float* __restrict__ xpf, float* __restrict__ xpb)
{
    __shared__ float As[64][66];
    __shared__ float Bs[64][66];
    const int bi = blockIdx.x;
    const int mb = bi / 24, nb = bi % 24;
    const int m0 = mb * 64, n0 = nb * 64;
    const int tid = threadIdx.x;
    const int tx = tid & 15, ty = tid >> 4;
    float acc[4][4] = {};

    for (int kc = 0; kc < 128; kc += 64) {
        __syncthreads();
        for (int it = 0; it < 4; ++it) {
            const int l  = it * 256 + tid;
            const int mi = l >> 4;
            const int k4 = (l & 15) << 2;
            const int row = x[m0 + mi];
            const float4 v = *(const float4*)(embed + (size_t)row * Ee + kc + k4);
            As[k4 + 0][mi] = v.x; As[k4 + 1][mi] = v.y;
            As[k4 + 2][mi] = v.z; As[k4 + 3][mi] = v.w;
        }
        for (int it = 0; it < 4; ++it) {
            const int l  = it * 256 + tid;
            const int ni = l >> 4;
            const int k4 = (l & 15) << 2;
            const int g  = n0 + ni;
            const float* wsrc = (g < G3) ? (wf + (size_t)g * Ee)
                                         : (wb + (size_t)(g - G3) * Ee);
            const float4 v = *(const float4*)(wsrc + kc + k4);
            Bs[k4 + 0][ni] = v.x; Bs[k4 + 1][ni] = v.y;
            Bs[k4 + 2][ni] = v.z; Bs[k4 + 3][ni] = v.w;
        }
        __syncthreads();
        for (int k = 0; k < 64; ++k) {
            const float a0 = As[k][ty];      const float a1 = As[k][ty + 16];
            const float a2 = As[k][ty + 32]; const float a3 = As[k][ty + 48];
            const float b0 = Bs[k][tx];      const float b1 = Bs[k][tx + 16];
            const float b2 = Bs[k][tx + 32]; const float b3 = Bs[k][tx + 48];
            acc[0][0] += a0 * b0; acc[0][1] += a0 * b1; acc[0][2] += a0 * b2; acc[0][3] += a0 * b3;
            acc[1][0] += a1 * b0; acc[1][1] += a1 * b1; acc[1][2] += a1 * b2; acc[1][3] += a1 * b3;
            acc[2][0] += a2 * b0; acc[2][1] += a2 * b1; acc[2][2] += a2 * b2; acc[2][3] += a2 * b3;
            acc[3][0] += a3 * b0; acc[3][1] += a3 * b1; acc[3][2] += a3 * b2; acc[3][3] += a3 * b3;
        }
    }
#pragma unroll
    for (int i = 0; i < 4; ++i) {
        const int m = m0 + ty + 16 * i;
#pragma unroll
        for (int c = 0; c < 4; ++c) {
            const int g = n0 + tx + 16 * c;
            const float v = acc[i][c];
            if (g < G3) {
                const float bias = bihf[g] + (g < 2 * Hq ? bhhf[g] : 0.0f);
                xpf[(size_t)m * G3 + g] = v + bias;
            } else {
                const int g2 = g - G3;
                const float bias = bihb[g2] + (g2 < 2 * Hq ? bhhb[g2] : 0.0f);
                xpb[(size_t)m * G3 + g2] = v + bias;
            }
        }
    }
}

// ---------------------------------------------------------------------------
// GRU recurrence, batch-amortized j-slice split.
// 256 blocks: js = bid>>5 (j-slice of 32 units), gid = bid&31 = (dir, bg).
// Each block computes h for its 32 units x 4 batches (b = bg*4+bl) with the
// weight slice (24 float4/thread) PERMANENTLY in VGPRs -- small enough that
// the allocator actually grants it (R6 precedent: 244 granted at 256thr/(1,1)).
// Weight memory traffic per step: ZERO. Per step the 8 j-slice blocks of a
// group exchange h halves via MALL (relaxed agent atomics; release flag;
// RELAXED polls only -- no L2 invalidates, the R9/R12 failure mechanism).
// Thread (jl = tid&31, ks = tid>>5): units jg=js*32+jl, k in [ks*32,ks*32+32).
__global__ __launch_bounds__(256, 1)
__attribute__((amdgpu_waves_per_eu(1, 1)))
void gru_kernel(const float* __restrict__ wtq0,
                float* __restrict__ xpf, float* __restrict__ xpb,
                const float* __restrict__ bhhf, const float* __restrict__ bhhb,
                float* __restrict__ slot, int* __restrict__ flags)
{
    __shared__ float hst[4][Hq];          // staged h, 4 batches     (4 KB)
    __shared__ float sh_p[8][3][4][32];   // [ks][gate][bl][jl]     (12 KB)

    const int bid = blockIdx.x;
    const int js  = bid >> 5;             // j-slice 0..7
    const int gid = bid & 31;             // group (dir, bg)
    const int dir = gid >> 4;
    const int bg  = gid & 15;
    const int tid = threadIdx.x;
    const int jl  = tid & 31;
    const int ks  = tid >> 5;             // 0..7
    const int jg  = js * 32 + jl;

    const float4* wtq4 = (const float4*)(wtq0 + (size_t)dir * (G3 * Hq));
    float* xp = dir ? xpb : xpf;

    // Register-resident weight slice: 3 gates x 8 quads (k = ks*32..ks*32+31)
    float4 wr[8], wz[8], wn[8];
#pragma unroll
    for (int qq = 0; qq < 8; ++qq) {
        const int Q = ks * 8 + qq;
        wr[qq] = wtq4[(Q * 3 + 0) * Hq + jg];
        wz[qq] = wtq4[(Q * 3 + 1) * Hq + jg];
        wn[qq] = wtq4[(Q * 3 + 2) * Hq + jg];
    }

    // combiner role: tid<128 -> (bl = tid>>5, jc = tid&31)
    const int blc = tid >> 5;             // valid when tid<128
    const int jc  = tid & 31;
    const int jgc = js * 32 + jc;
    const float bhn = (dir ? bhhb : bhhf)[2 * Hq + jgc];
    const int fbase = gid * 8;
    const int oflag = fbase + js;
    float hprev = 0.0f;

    for (int ti = 0; ti < Tt; ++ti) {
        const int t = dir ? (Tt - 1 - ti) : ti;

        // x parts for combiners -- issued early, hide under poll+stage
        float xr = 0.f, xz = 0.f, xn = 0.f;
        float* xw = 0;
        if (tid < 128) {
            xw = xp + ((size_t)(bg * 4 + blc) * Tt + t) * G3;
            xr = xw[jgc];
            xz = xw[Hq + jgc];
            xn = xw[2 * Hq + jgc];
        }

        float ar[4] = {0.f, 0.f, 0.f, 0.f};
        float az[4] = {0.f, 0.f, 0.f, 0.f};
        float an[4] = {0.f, 0.f, 0.f, 0.f};

        if (ti > 0) {
            // ---- wait for the group's h(ti): RELAXED polls only ----
            if (tid == 0) {
                for (;;) {
                    bool ok = true;
#pragma unroll
                    for (int q = 0; q < 8; ++q)
                        ok &= (__hip_atomic_load(&flags[fbase + q],
                                                 __ATOMIC_RELAXED,
                                                 __HIP_MEMORY_SCOPE_AGENT) >= ti);
                    if (ok) break;
                    __builtin_amdgcn_s_sleep(1);
                }
            }
            __syncthreads();
            // ---- stage slot -> hst (1024 floats, 4/thread, MALL atomics) ----
            {
                const int par = ti & 1;
                const float* sb = slot + ((size_t)(par * 2 + dir) * 64 + bg * 4) * Hq;
                float4 v;
                v.x = __hip_atomic_load(&sb[tid * 4 + 0], __ATOMIC_RELAXED, __HIP_MEMORY_SCOPE_AGENT);
                v.y = __hip_atomic_load(&sb[tid * 4 + 1], __ATOMIC_RELAXED, __HIP_MEMORY_SCOPE_AGENT);
                v.z = __hip_atomic_load(&sb[tid * 4 + 2], __ATOMIC_RELAXED, __HIP_MEMORY_SCOPE_AGENT);
                v.w = __hip_atomic_load(&sb[tid * 4 + 3], __ATOMIC_RELAXED, __HIP_MEMORY_SCOPE_AGENT);
                ((float4*)&hst[0][0])[tid] = v;
            }
            __syncthreads();
            // ---- dot phase: weights in VGPRs, h broadcast from LDS ----
#pragma unroll
            for (int qq = 0; qq < 8; ++qq) {
#pragma unroll
                for (int bl = 0; bl < 4; ++bl) {
                    const float4 h4 = *(const float4*)&hst[bl][(ks * 8 + qq) * 4];
                    ar[bl] += h4.x * wr[qq].x + h4.y * wr[qq].y + h4.z * wr[qq].z + h4.w * wr[qq].w;
                    az[bl] += h4.x * wz[qq].x + h4.y * wz[qq].y + h4.z * wz[qq].z + h4.w * wz[qq].w;
                    an[bl] += h4.x * wn[qq].x + h4.y * wn[qq].y + h4.z * wn[qq].z + h4.w * wn[qq].w;
                }
            }
        }

        // ---- k-reduction partials ----
#pragma unroll
        for (int bl = 0; bl < 4; ++bl) {
            sh_p[ks][0][bl][jl] = ar[bl];
            sh_p[ks][1][bl][jl] = az[bl];
            sh_p[ks][2][bl][jl] = an[bl];
        }
        __syncthreads();

        // ---- combine + publish ----
        if (tid < 128) {
            float fr = 0.f, fz = 0.f, fn = 0.f;
#pragma unroll
            for (int q = 0; q < 8; ++q) {
                fr += sh_p[q][0][blc][jc];
                fz += sh_p[q][1][blc][jc];
                fn += sh_p[q][2][blc][jc];
            }
            const float r = 1.0f / (1.0f + expf(-(xr + fr)));
            const float z = 1.0f / (1.0f + expf(-(xz + fz)));
            const float n = tanhf(xn + r * (fn + bhn));
            const float hnew = (1.0f - z) * n + z * hprev;
            hprev = hnew;
            xw[jgc] = hnew;                       // in-place h store (for em)
            const int par = (ti + 1) & 1;
            __hip_atomic_store(
                &slot[((size_t)(par * 2 + dir) * 64 + bg * 4 + blc) * Hq + jgc],
                hnew, __ATOMIC_RELAXED, __HIP_MEMORY_SCOPE_AGENT);
        }
        __syncthreads();   // all combiners' slot stores issued before release
        if (tid == 0)
            __hip_atomic_store(&flags[oflag], ti + 1, __ATOMIC_RELEASE,
                               __HIP_MEMORY_SCOPE_AGENT);
    }
}

// ---------------------------------------------------------------------------
// em[m][n] = sum_k hf[m][k]*fcw[n][k] + sum_k hb[m][k]*fcw[n][256+k] + fcb[n]
__global__ __launch_bounds__(256) void em_kernel(
    const float* __restrict__ hf, const float* __restrict__ hb,
    const float* __restrict__ fcw, const float* __restrict__ fcb,
    float* __restrict__ em)
{
    __shared__ float ht[16][129];
    __shared__ float wt2[16][129];
    const int m0 = blockIdx.x * 16;
    const int tid = threadIdx.x;
    const int r = tid >> 4, n = tid & 15;
    float acc = 0.0f;
    for (int s = 0; s < 2; ++s) {
        const float* src = s ? hb : hf;
        for (int kc = 0; kc < Hq; kc += 128) {
            __syncthreads();
            for (int it = 0; it < 8; ++it) {
                const int l = it * 256 + tid;
                const int rr = l >> 7, k = l & 127;
                ht[rr][k] = src[(size_t)(m0 + rr) * G3 + kc + k];
            }
            for (int it = 0; it < 8; ++it) {
                const int l = it * 256 + tid;
                const int rr = l >> 7, k = l & 127;
                wt2[rr][k] = fcw[(size_t)rr * (2 * Hq) + s * Hq + kc + k];
            }
            __syncthreads();
            for (int k = 0; k < 128; ++k)
                acc += ht[r][k] * wt2[n][k];
        }
    }
    em[(size_t)(m0 + r) * KK + n] = acc + fcb[n];
}

// ---------------------------------------------------------------------------
// Viterbi: one wave per batch. Lanes 0..15 = states. Backpointers in LDS.
__global__ __launch_bounds__(64) void viterbi_kernel(
    const float* __restrict__ em, const int* __restrict__ y,
    const float* __restrict__ tr, float* __restrict__ out)
{
    __shared__ unsigned char bps[(Tt - 1) * KK];
    __shared__ unsigned char msk[Tt];
    const int b = blockIdx.x;
    const int lane = threadIdx.x;
    if (lane >= KK) return;
    const int j = lane;
    float tc[KK];
#pragma unroll
    for (int i = 0; i < KK; ++i) tc[i] = tr[i * KK + j];
    const float* erow = em + (size_t)b * Tt * KK;
    const int* yrow = y + b * Tt;
    float s = tr[1 * KK + j] + erow[j];            // BOS row + em[:,0]
    if (j == 0) msk[0] = (unsigned char)(yrow[0] != 0);
    float e1 = erow[1 * KK + j];  int y1v = yrow[1];
    float e2 = erow[2 * KK + j];  int y2v = yrow[2];
    for (int t = 1; t < Tt; ++t) {
        const float e = e1; const int yt = y1v;
        e1 = e2; y1v = y2v;
        if (t + 2 < Tt) { e2 = erow[(size_t)(t + 2) * KK + j]; y2v = yrow[t + 2]; }
        float best = -3.0e38f; int arg = 0;
#pragma unroll
        for (int i = 0; i < KK; ++i) {
            const float si = __shfl(s, i, KK);
            const float c = si + tc[i];
            if (c > best) { best = c; arg = i; }   // strict >, first-max = argmax
        }
        best += e;
        const bool m = (yt != 0);
        if (m) s = best;
        bps[(t - 1) * KK + j] = m ? (unsigned char)arg : (unsigned char)j;
        if (j == 0) msk[t] = (unsigned char)m;
    }
    s += tr[j * KK + 2];                           // + trans[:,EOS]
    float bs = -3.0e38f; int bt = 0;
#pragma unroll
    for (int i = 0; i < KK; ++i) {
        const float si = __shfl(s, i, KK);
        if (si > bs) { bs = si; bt = i; }
    }
    if (j == 0) {
        out[b] = bs;
        float* path = out + Bb + (size_t)b * Tt;
        int tag = bt;
        path[Tt - 1] = msk[Tt - 1] ? (float)tag : 0.0f;
        for (int t = Tt - 2; t >= 0; --t) {
            tag = bps[t * KK + tag];
            path[t] = msk[t] ? (float)tag : 0.0f;
        }
    }
}

// Diagnostic fallback if workspace is too small: park ws_size in out[0..63].
__global__ void ws_report_kernel(float* out, float v)
{
    if (threadIdx.x < 64) out[threadIdx.x] = v;
}

// ---------------------------------------------------------------------------
extern "C" void kernel_launch(void* const* d_in, const int* in_sizes, int n_in,
                              void* d_out, int out_size, void* d_ws, size_t ws_size,
                              hipStream_t stream)
{
    const int*   x     = (const int*)d_in[0];
    const int*   y     = (const int*)d_in[1];
    const float* emb   = (const float*)d_in[2];
    const float* wihf  = (const float*)d_in[3];
    const float* whhf  = (const float*)d_in[4];
    const float* bihf  = (const float*)d_in[5];
    const float* bhhf  = (const float*)d_in[6];
    const float* wihb  = (const float*)d_in[7];
    const float* whhb  = (const float*)d_in[8];
    const float* bihb  = (const float*)d_in[9];
    const float* bhhb  = (const float*)d_in[10];
    const float* fcw   = (const float*)d_in[11];
    const float* fcb   = (const float*)d_in[12];
    const float* trans = (const float*)d_in[13];
    float* out = (float*)d_out;
    float* ws  = (float*)d_ws;

    if (ws_size < WS_FLOATS * sizeof(float)) {
        ws_report_kernel<<<1, 64, 0, stream>>>(out, (float)ws_size);
        return;
    }

    // reset group-sync flags (stale from previous replay / poisoned)
    hipMemsetAsync(ws + OFF_FLAG, 0, 256 * sizeof(int), stream);

    transpose_whh<<<768, 256, 0, stream>>>(whhf, ws + OFF_WTF);
    transpose_whh<<<768, 256, 0, stream>>>(whhb, ws + OFF_WTB);
    proj_kernel<<<12288, 256, 0, stream>>>(x, emb, wihf, wihb,
                                           bihf, bhhf, bihb, bhhb,
                                           ws + OFF_XPF, ws + OFF_XPB);
    gru_kernel<<<256, 256, 0, stream>>>(ws + OFF_WTF,
                                        ws + OFF_XPF, ws + OFF_XPB,
                                        bhhf, bhhb,
                                        ws + OFF_SLOT,
                                        (int*)(ws + OFF_FLAG));
    em_kernel<<<2048, 256, 0, stream>>>(ws + OFF_XPF, ws + OFF_XPB, fcw, fcb,
                                        ws + OFF_EM);
    viterbi_kernel<<<64, 64, 0, stream>>>(ws + OFF_EM, y, trans, out);
}

// Round 15
// 2512.077 us; speedup vs baseline: 2.0612x; 1.5966x over previous
//
#include <hip/hip_runtime.h>
#include <math.h>

// Problem constants
#define Bb 64
#define Tt 512
#define Ee 128
#define Hq 256
#define G3 768      // 3*H
#define KK 16

// GRU tuning (R7-proven skeleton): per-thread k-range = 128 (half) = 32 quads:
//   RQ quads "preloaded" (compiler rematerializes into a hoisted batch of 36
//   independent loads each step -> the MLP engine), LQ quads in dynamic LDS
//   (staged once, reused 512 steps), rest streamed from L2 with SHALLOW
//   unroll (2) so in-flight data fits the ~116-VGPR allocation (R11's
//   unroll-7 = 84 regs in flight = serialization, the measured regression).
#define THR 512
#define RQ 12
#define LQ 6
#define NSQ (32 - RQ - LQ)                 // 14 streamed quads
#define LDSW_ROWS (2 * LQ * 3)             // 36 rows of [256] float4
#define LDSW_BYTES (LDSW_ROWS * Hq * 16)   // 147456 B

// Workspace layout (in floats).  Budget: 256 MiB.
#define OFF_WTF  0
#define OFF_WTB  196608                        // 768*256
#define OFF_XPF  393216
#define OFF_XPB  (OFF_XPF + 25165824)          // 32768*768
#define OFF_EM   (OFF_XPB + 25165824)
#define WS_FLOATS ((size_t)(OFF_EM + 524288))  // 205 MB

// ---------------------------------------------------------------------------
// Repack w_hh (768x256, row g3 = gate*256+j, col k) into quad-gate layout:
//   float4 at index (Q*3+gate)*256+j holds w[gate,j][4Q..4Q+3].
__global__ __launch_bounds__(256) void transpose_whh(const float* __restrict__ w,
                                                     float* __restrict__ wt)
{
    const int idx = blockIdx.x * 256 + threadIdx.x;
    if (idx < G3 * Hq) {
        const int g3 = idx >> 8;       // 0..767
        const int k  = idx & 255;      // 0..255
        const int gate = g3 >> 8;      // 0..2
        const int j    = g3 & 255;
        const int Q = k >> 2, e = k & 3;
        wt[(size_t)(((Q * 3 + gate) << 8) + j) * 4 + e] = w[idx];
    }
}

// ---------------------------------------------------------------------------
// Fused embedding-gather + input projection for both directions.
__global__ __launch_bounds__(256) void proj_kernel(
    const int* __restrict__ x, const float* __restrict__ embed,
    const float* __restrict__ wf, const float* __restrict__ wb,
    const float* __restrict__ bihf, const float* __restrict__ bhhf,
    const float* __restrict__ bihb, const float* __restrict__ bhhb,
    float* __restrict__ xpf, float* __restrict__ xpb)
{
    __shared__ float As[64][66];
    __shared__ float Bs[64][66];
    const int bi = blockIdx.x;
    const int mb = bi / 24, nb = bi % 24;
    const int m0 = mb * 64, n0 = nb * 64;
    const int tid = threadIdx.x;
    const int tx = tid & 15, ty = tid >> 4;
    float acc[4][4] = {};

    for (int kc = 0; kc < 128; kc += 64) {
        __syncthreads();
        for (int it = 0; it < 4; ++it) {
            const int l  = it * 256 + tid;
            const int mi = l >> 4;
            const int k4 = (l & 15) << 2;
            const int row = x[m0 + mi];
            const float4 v = *(const float4*)(embed + (size_t)row * Ee + kc + k4);
            As[k4 + 0][mi] = v.x; As[k4 + 1][mi] = v.y;
            As[k4 + 2][mi] = v.z; As[k4 + 3][mi] = v.w;
        }
        for (int it = 0; it < 4; ++it) {
            const int l  = it * 256 + tid;
            const int ni = l >> 4;
            const int k4 = (l & 15) << 2;
            const int g  = n0 + ni;
            const float* wsrc = (g < G3) ? (wf + (size_t)g * Ee)
                                         : (wb + (size_t)(g - G3) * Ee);
            const float4 v = *(const float4*)(wsrc + kc + k4);
            Bs[k4 + 0][ni] = v.x; Bs[k4 + 1][ni] = v.y;
            Bs[k4 + 2][ni] = v.z; Bs[k4 + 3][ni] = v.w;
        }
        __syncthreads();
        for (int k = 0; k < 64; ++k) {
            const float a0 = As[k][ty];      const float a1 = As[k][ty + 16];
            const float a2 = As[k][ty + 32]; const float a3 = As[k][ty + 48];
            const float b0 = Bs[k][tx];      const float b1 = Bs[k][tx + 16];
            const float b2 = Bs[k][tx + 32]; const float b3 = Bs[k][tx + 48];
            acc[0][0] += a0 * b0; acc[0][1] += a0 * b1; acc[0][2] += a0 * b2; acc[0][3] += a0 * b3;
            acc[1][0] += a1 * b0; acc[1][1] += a1 * b1; acc[1][2] += a1 * b2; acc[1][3] += a1 * b3;
            acc[2][0] += a2 * b0; acc[2][1] += a2 * b1; acc[2][2] += a2 * b2; acc[2][3] += a2 * b3;
            acc[3][0] += a3 * b0; acc[3][1] += a3 * b1; acc[3][2] += a3 * b2; acc[3][3] += a3 * b3;
        }
    }
#pragma unroll
    for (int i = 0; i < 4; ++i) {
        const int m = m0 + ty + 16 * i;
#pragma unroll
        for (int c = 0; c < 4; ++c) {
            const int g = n0 + tx + 16 * c;
            const float v = acc[i][c];
            if (g < G3) {
                const float bias = bihf[g] + (g < 2 * Hq ? bhhf[g] : 0.0f);
                xpf[(size_t)m * G3 + g] = v + bias;
            } else {
                const int g2 = g - G3;
                const float bias = bihb[g2] + (g2 < 2 * Hq ? bhhb[g2] : 0.0f);
                xpb[(size_t)m * G3 + g2] = v + bias;
            }
        }
    }
}

// ---------------------------------------------------------------------------
// GRU recurrence, split-k (exact R7 skeleton; only LQ grew 2->6).
// 128 blocks x 512 thr (8 waves, 2/SIMD). Thread (j = tid&255, half = tid>>8):
// r,z,n partial dots over 32 quads. Quads 0..RQ-1: "preload" arrays (remat
// -> hoisted independent-load batch). RQ..RQ+LQ-1: dynamic LDS. Rest:
// streamed from L2, unroll 2. Two barriers/step. No cross-block sync.
__global__ __launch_bounds__(THR, 1)
__attribute__((amdgpu_waves_per_eu(2, 2)))
void gru_kernel(const float* __restrict__ wtq0,
                float* __restrict__ xpf, float* __restrict__ xpb,
                const float* __restrict__ bhhf, const float* __restrict__ bhhb)
{
    extern __shared__ float4 sh_w[];           // [36][256] float4 = 144 KB
    __shared__ float sh_h[2][Hq];              // 2 KB
    __shared__ float sh_p[2][3][Hq];           // 6 KB

    const int bid  = blockIdx.x;
    const int dir  = bid >> 6;
    const int b    = bid & 63;
    const int tid  = threadIdx.x;
    const int j    = tid & 255;
    const int half = tid >> 8;

    const float4* wtq = (const float4*)(wtq0 + (size_t)dir * (G3 * Hq));
    float* xp = (dir ? xpb : xpf) + (size_t)b * Tt * G3;

    // "VGPR" weights: quads q in [0, RQ)  (rematerialized -> prefetch batch)
    float wrv[4 * RQ], wzv[4 * RQ], wnv[4 * RQ];
#pragma unroll
    for (int q = 0; q < RQ; ++q) {
        const int Q = half * 32 + q;
        const float4 vr = wtq[(Q * 3 + 0) * Hq + j];
        const float4 vz = wtq[(Q * 3 + 1) * Hq + j];
        const float4 vn = wtq[(Q * 3 + 2) * Hq + j];
        wrv[4*q]=vr.x; wrv[4*q+1]=vr.y; wrv[4*q+2]=vr.z; wrv[4*q+3]=vr.w;
        wzv[4*q]=vz.x; wzv[4*q+1]=vz.y; wzv[4*q+2]=vz.z; wzv[4*q+3]=vz.w;
        wnv[4*q]=vn.x; wnv[4*q+1]=vn.y; wnv[4*q+2]=vn.z; wnv[4*q+3]=vn.w;
    }

    // Stage LDS weight cache: row = (hw*LQ + ql)*3 + gate, quad Q = hw*32+RQ+ql
    for (int idx = tid; idx < LDSW_ROWS * Hq; idx += THR) {
        const int row = idx >> 8;
        const int jj  = idx & 255;
        const int gate = row % 3;
        const int qg   = row / 3;          // 0 .. 2*LQ-1
        const int hw   = qg / LQ;
        const int ql   = qg % LQ;
        const int Q    = hw * 32 + RQ + ql;
        sh_w[(size_t)row * Hq + jj] = wtq[(Q * 3 + gate) * Hq + jj];
    }

    const float bhn = (dir ? bhhb : bhhf)[2 * Hq + j];
    float hprev = 0.0f;
    if (tid < Hq) sh_h[0][tid] = 0.0f;
    __syncthreads();

    int cur = 0;
    for (int ti = 0; ti < Tt; ++ti) {
        const int t = dir ? (Tt - 1 - ti) : ti;
        float* xrow = xp + (size_t)t * G3;

        // prefetch x parts (combiner threads)
        float xr = 0.f, xz = 0.f, xn = 0.f;
        if (tid < Hq) {
            xr = xrow[tid];
            xz = xrow[Hq + tid];
            xn = xrow[2 * Hq + tid];
        }

        const float4* hb4 = (const float4*)(sh_h[cur] + half * 128);
        float ar = 0.0f, az = 0.0f, an = 0.0f;

        // 1) "VGPR" quads (hoisted independent-load batch = MLP engine)
#pragma unroll
        for (int q = 0; q < RQ; ++q) {
            const float4 h4 = hb4[q];
            ar += h4.x*wrv[4*q] + h4.y*wrv[4*q+1] + h4.z*wrv[4*q+2] + h4.w*wrv[4*q+3];
            az += h4.x*wzv[4*q] + h4.y*wzv[4*q+1] + h4.z*wzv[4*q+2] + h4.w*wzv[4*q+3];
            an += h4.x*wnv[4*q] + h4.y*wnv[4*q+1] + h4.z*wnv[4*q+2] + h4.w*wnv[4*q+3];
        }
        // 2) LDS-cached quads
#pragma unroll
        for (int ql = 0; ql < LQ; ++ql) {
            const float4 h4 = hb4[RQ + ql];
            const int row = (half * LQ + ql) * 3;
            const float4 vr = sh_w[(size_t)(row + 0) * Hq + j];
            const float4 vz = sh_w[(size_t)(row + 1) * Hq + j];
            const float4 vn = sh_w[(size_t)(row + 2) * Hq + j];
            ar += h4.x*vr.x + h4.y*vr.y + h4.z*vr.z + h4.w*vr.w;
            az += h4.x*vz.x + h4.y*vz.y + h4.z*vz.z + h4.w*vz.w;
            an += h4.x*vn.x + h4.y*vn.y + h4.z*vn.z + h4.w*vn.w;
        }
        // 3) streamed quads from L2 (shallow unroll: 6 float4 in flight)
        {
            const float4* pw = wtq + ((half * 32 + RQ + LQ) * 3) * Hq + j;
#pragma unroll 2
            for (int qs = 0; qs < NSQ; ++qs) {
                const float4 vr = pw[0];
                const float4 vz = pw[Hq];
                const float4 vn = pw[2 * Hq];
                const float4 h4 = hb4[RQ + LQ + qs];
                ar += h4.x*vr.x + h4.y*vr.y + h4.z*vr.z + h4.w*vr.w;
                az += h4.x*vz.x + h4.y*vz.y + h4.z*vz.z + h4.w*vz.w;
                an += h4.x*vn.x + h4.y*vn.y + h4.z*vn.z + h4.w*vn.w;
                pw += 3 * Hq;
            }
        }

        sh_p[half][0][j] = ar;
        sh_p[half][1][j] = az;
        sh_p[half][2][j] = an;
        __syncthreads();

        if (tid < Hq) {
            const float far_ = sh_p[0][0][tid] + sh_p[1][0][tid];
            const float faz_ = sh_p[0][1][tid] + sh_p[1][1][tid];
            const float fan_ = sh_p[0][2][tid] + sh_p[1][2][tid];
            const float r = 1.0f / (1.0f + expf(-(xr + far_)));
            const float z = 1.0f / (1.0f + expf(-(xz + faz_)));
            const float n = tanhf(xn + r * (fan_ + bhn));
            const float hnew = (1.0f - z) * n + z * hprev;
            hprev = hnew;
            sh_h[cur ^ 1][tid] = hnew;
            xrow[tid] = hnew;              // in-place h store
        }
        __syncthreads();
        cur ^= 1;
    }
}

// ---------------------------------------------------------------------------
// em[m][n] = sum_k hf[m][k]*fcw[n][k] + sum_k hb[m][k]*fcw[n][256+k] + fcb[n]
__global__ __launch_bounds__(256) void em_kernel(
    const float* __restrict__ hf, const float* __restrict__ hb,
    const float* __restrict__ fcw, const float* __restrict__ fcb,
    float* __restrict__ em)
{
    __shared__ float ht[16][129];
    __shared__ float wt2[16][129];
    const int m0 = blockIdx.x * 16;
    const int tid = threadIdx.x;
    const int r = tid >> 4, n = tid & 15;
    float acc = 0.0f;
    for (int s = 0; s < 2; ++s) {
        const float* src = s ? hb : hf;
        for (int kc = 0; kc < Hq; kc += 128) {
            __syncthreads();
            for (int it = 0; it < 8; ++it) {
                const int l = it * 256 + tid;
                const int rr = l >> 7, k = l & 127;
                ht[rr][k] = src[(size_t)(m0 + rr) * G3 + kc + k];
            }
            for (int it = 0; it < 8; ++it) {
                const int l = it * 256 + tid;
                const int rr = l >> 7, k = l & 127;
                wt2[rr][k] = fcw[(size_t)rr * (2 * Hq) + s * Hq + kc + k];
            }
            __syncthreads();
            for (int k = 0; k < 128; ++k)
                acc += ht[r][k] * wt2[n][k];
        }
    }
    em[(size_t)(m0 + r) * KK + n] = acc + fcb[n];
}

// ---------------------------------------------------------------------------
// Viterbi: one wave per batch. Lanes 0..15 = states. Backpointers in LDS.
__global__ __launch_bounds__(64) void viterbi_kernel(
    const float* __restrict__ em, const int* __restrict__ y,
    const float* __restrict__ tr, float* __restrict__ out)
{
    __shared__ unsigned char bps[(Tt - 1) * KK];
    __shared__ unsigned char msk[Tt];
    const int b = blockIdx.x;
    const int lane = threadIdx.x;
    if (lane >= KK) return;
    const int j = lane;
    float tc[KK];
#pragma unroll
    for (int i = 0; i < KK; ++i) tc[i] = tr[i * KK + j];
    const float* erow = em + (size_t)b * Tt * KK;
    const int* yrow = y + b * Tt;
    float s = tr[1 * KK + j] + erow[j];            // BOS row + em[:,0]
    if (j == 0) msk[0] = (unsigned char)(yrow[0] != 0);
    float e1 = erow[1 * KK + j];  int y1v = yrow[1];
    float e2 = erow[2 * KK + j];  int y2v = yrow[2];
    for (int t = 1; t < Tt; ++t) {
        const float e = e1; const int yt = y1v;
        e1 = e2; y1v = y2v;
        if (t + 2 < Tt) { e2 = erow[(size_t)(t + 2) * KK + j]; y2v = yrow[t + 2]; }
        float best = -3.0e38f; int arg = 0;
#pragma unroll
        for (int i = 0; i < KK; ++i) {
            const float si = __shfl(s, i, KK);
            const float c = si + tc[i];
            if (c > best) { best = c; arg = i; }   // strict >, first-max = argmax
        }
        best += e;
        const bool m = (yt != 0);
        if (m) s = best;
        bps[(t - 1) * KK + j] = m ? (unsigned char)arg : (unsigned char)j;
        if (j == 0) msk[t] = (unsigned char)m;
    }
    s += tr[j * KK + 2];                           // + trans[:,EOS]
    float bs = -3.0e38f; int bt = 0;
#pragma unroll
    for (int i = 0; i < KK; ++i) {
        const float si = __shfl(s, i, KK);
        if (si > bs) { bs = si; bt = i; }
    }
    if (j == 0) {
        out[b] = bs;
        float* path = out + Bb + (size_t)b * Tt;
        int tag = bt;
        path[Tt - 1] = msk[Tt - 1] ? (float)tag : 0.0f;
        for (int t = Tt - 2; t >= 0; --t) {
            tag = bps[t * KK + tag];
            path[t] = msk[t] ? (float)tag : 0.0f;
        }
    }
}

// Diagnostic fallback if workspace is too small: park ws_size in out[0..63].
__global__ void ws_report_kernel(float* out, float v)
{
    if (threadIdx.x < 64) out[threadIdx.x] = v;
}

// ---------------------------------------------------------------------------
extern "C" void kernel_launch(void* const* d_in, const int* in_sizes, int n_in,
                              void* d_out, int out_size, void* d_ws, size_t ws_size,
                              hipStream_t stream)
{
    const int*   x     = (const int*)d_in[0];
    const int*   y     = (const int*)d_in[1];
    const float* emb   = (const float*)d_in[2];
    const float* wihf  = (const float*)d_in[3];
    const float* whhf  = (const float*)d_in[4];
    const float* bihf  = (const float*)d_in[5];
    const float* bhhf  = (const float*)d_in[6];
    const float* wihb  = (const float*)d_in[7];
    const float* whhb  = (const float*)d_in[8];
    const float* bihb  = (const float*)d_in[9];
    const float* bhhb  = (const float*)d_in[10];
    const float* fcw   = (const float*)d_in[11];
    const float* fcb   = (const float*)d_in[12];
    const float* trans = (const float*)d_in[13];
    float* out = (float*)d_out;
    float* ws  = (float*)d_ws;

    if (ws_size < WS_FLOATS * sizeof(float)) {
        ws_report_kernel<<<1, 64, 0, stream>>>(out, (float)ws_size);
        return;
    }

    transpose_whh<<<768, 256, 0, stream>>>(whhf, ws + OFF_WTF);
    transpose_whh<<<768, 256, 0, stream>>>(whhb, ws + OFF_WTB);
    proj_kernel<<<12288, 256, 0, stream>>>(x, emb, wihf, wihb,
                                           bihf, bhhf, bihb, bhhb,
                                           ws + OFF_XPF, ws + OFF_XPB);
    gru_kernel<<<128, THR, LDSW_BYTES, stream>>>(ws + OFF_WTF,
                                                 ws + OFF_XPF, ws + OFF_XPB,
                                                 bhhf, bhhb);
    em_kernel<<<2048, 256, 0, stream>>>(ws + OFF_XPF, ws + OFF_XPB, fcw, fcb,
                                        ws + OFF_EM);
    viterbi_kernel<<<64, 64, 0, stream>>>(ws + OFF_EM, y, trans, out);
}